// Round 1
// baseline (352.024 us; speedup 1.0000x reference)
//
#include <hip/hip_runtime.h>
#include <hip/hip_bf16.h>
#include <math.h>

// ---------------------------------------------------------------------------
// HybridQuantumKernelNet forward, fp32 throughout.
// Shapes: x[64,3,250,250] -> conv1(6,5x5,s2,p1)+relu -> [64,6,124,124]
//         maxpool2 s1 -> [64,6,123,123]
//         conv2(15,3x3,s2,p1)+relu -> [64,15,62,62] -> maxpool2 s1 -> [64,15,61,61]
//         flatten K=55815 -> fc1(120)+relu -> fc2(84)+relu -> fc3(1)
//         quantum head: cos((z-p)/2)^4 @ kh_w + kh_b -> sigmoid -> [p,1-p]
// ---------------------------------------------------------------------------

#define B_IMG 64
#define KTOT 55815            // 15*61*61
#define P1H 123               // pooled1 spatial
#define P2H 61                // pooled2 spatial
#define NCHUNK 437            // ceil(55815/128)

// ---------------- Kernel 1: conv1 + relu + maxpool(2,s1) fused -------------
// Conv tile 16x16 (=256 threads, 1 position each) -> pooled tile 15x15.
// Grid: (9*9 tiles, 64 images). Inputs cached in 75 VGPRs; weights are
// wave-uniform scalar loads (oc,i are unrolled constants).
__global__ __launch_bounds__(256) void conv1_pool(
    const float* __restrict__ x, const float* __restrict__ w,
    const float* __restrict__ bias, float* __restrict__ out) {
  __shared__ float cs[6][16][16];
  const int b = blockIdx.y;
  const int ty = blockIdx.x / 9, tx = blockIdx.x % 9;
  const int py0 = ty * 15, px0 = tx * 15;
  const int tid = threadIdx.x;
  const int cyl = tid >> 4, cxl = tid & 15;
  const int cy = py0 + cyl, cx = px0 + cxl;      // conv output coords
  const float* xb = x + b * 187500;              // 3*250*250
  const bool cv = (cy < 124) && (cx < 124);
  const int iy0 = 2 * cy - 1, ix0 = 2 * cx - 1;  // pad=1, stride=2

  float rin[75];
#pragma unroll
  for (int ic = 0; ic < 3; ++ic) {
    const float* xc = xb + ic * 62500;
#pragma unroll
    for (int ky = 0; ky < 5; ++ky) {
      const int iy = iy0 + ky;
#pragma unroll
      for (int kx = 0; kx < 5; ++kx) {
        const int ix = ix0 + kx;
        // cy<124 -> iy<=249 in-bounds; only low-side check needed.
        const bool ok = cv && (iy >= 0) && (ix >= 0);
        rin[ic * 25 + ky * 5 + kx] = ok ? xc[iy * 250 + ix] : 0.0f;
      }
    }
  }
#pragma unroll
  for (int oc = 0; oc < 6; ++oc) {
    float a = bias[oc];
#pragma unroll
    for (int i = 0; i < 75; ++i) a = fmaf(rin[i], w[oc * 75 + i], a);
    cs[oc][cyl][cxl] = fmaxf(a, 0.0f);
  }
  __syncthreads();
  if (tid < 225) {
    const int pyl = tid / 15, pxl = tid % 15;
    const int py = py0 + pyl, px = px0 + pxl;
    if (py < P1H && px < P1H) {
      float* ob = out + b * (6 * P1H * P1H);
#pragma unroll
      for (int oc = 0; oc < 6; ++oc) {
        const float v = fmaxf(fmaxf(cs[oc][pyl][pxl], cs[oc][pyl][pxl + 1]),
                              fmaxf(cs[oc][pyl + 1][pxl], cs[oc][pyl + 1][pxl + 1]));
        ob[oc * (P1H * P1H) + py * P1H + px] = v;
      }
    }
  }
}

// ---------------- Kernel 2: conv2 + relu + maxpool(2,s1) fused -------------
// Grid: (5*5 tiles, 64 images). Output written in flatten order [b][c][y][x].
__global__ __launch_bounds__(256) void conv2_pool(
    const float* __restrict__ in, const float* __restrict__ w,
    const float* __restrict__ bias, float* __restrict__ A) {
  __shared__ float cs[15][16][16];
  const int b = blockIdx.y;
  const int ty = blockIdx.x / 5, tx = blockIdx.x % 5;
  const int py0 = ty * 15, px0 = tx * 15;
  const int tid = threadIdx.x;
  const int cyl = tid >> 4, cxl = tid & 15;
  const int cy = py0 + cyl, cx = px0 + cxl;
  const float* ib = in + b * (6 * P1H * P1H);
  const bool cv = (cy < 62) && (cx < 62);
  const int iy0 = 2 * cy - 1, ix0 = 2 * cx - 1;

  float rin[54];
#pragma unroll
  for (int ic = 0; ic < 6; ++ic) {
    const float* icp = ib + ic * (P1H * P1H);
#pragma unroll
    for (int ky = 0; ky < 3; ++ky) {
      const int iy = iy0 + ky;
#pragma unroll
      for (int kx = 0; kx < 3; ++kx) {
        const int ix = ix0 + kx;
        const bool ok = cv && (iy >= 0) && (iy < P1H) && (ix >= 0) && (ix < P1H);
        rin[ic * 9 + ky * 3 + kx] = ok ? icp[iy * P1H + ix] : 0.0f;
      }
    }
  }
#pragma unroll
  for (int oc = 0; oc < 15; ++oc) {
    float a = bias[oc];
#pragma unroll
    for (int i = 0; i < 54; ++i) a = fmaf(rin[i], w[oc * 54 + i], a);
    cs[oc][cyl][cxl] = fmaxf(a, 0.0f);
  }
  __syncthreads();
  if (tid < 225) {
    const int pyl = tid / 15, pxl = tid % 15;
    const int py = py0 + pyl, px = px0 + pxl;
    if (py < P2H && px < P2H) {
      float* ob = A + b * KTOT;
#pragma unroll
      for (int oc = 0; oc < 15; ++oc) {
        const float v = fmaxf(fmaxf(cs[oc][pyl][pxl], cs[oc][pyl][pxl + 1]),
                              fmaxf(cs[oc][pyl + 1][pxl], cs[oc][pyl + 1][pxl + 1]));
        ob[oc * (P2H * P2H) + py * P2H + px] = v;
      }
    }
  }
}

// ---------------- Kernel 3: fc1 split-K partials ---------------------------
// One block per K-chunk of 128. A-chunk staged in LDS [64][129] (stride 129
// => column read bank = (m+k)%32, conflict-free). Wave w computes columns
// n0=w*30..+29 for all 64 rows: lane=m, per k: 1 ds_read + 30 scalar-W FMAs.
// Partials layout [chunk][n][m] -> coalesced writes and coalesced reduce.
__global__ __launch_bounds__(256) void fc1_partial(
    const float* __restrict__ A, const float* __restrict__ W,
    float* __restrict__ part) {
  __shared__ float As[64][129];
  const int tid = threadIdx.x;
  const int chunk = blockIdx.x;
  const int k0 = chunk * 128;
  const int kc = min(128, KTOT - k0);

  // Stage A[0:64][k0:k0+kc] -> LDS. thread t: row m=t>>2, 8 float4 loads.
  {
    const int m = tid >> 2, q = tid & 3;
    const float* Am = A + m * KTOT + k0;
#pragma unroll
    for (int s = 0; s < 8; ++s) {
      const int kk = (s * 4 + q) * 4;   // 4 threads cover 64B contiguous
      float4 v;
      if (kk + 4 <= kc) {
        v = *reinterpret_cast<const float4*>(Am + kk);
      } else {
        v.x = (kk + 0 < kc) ? Am[kk + 0] : 0.0f;
        v.y = (kk + 1 < kc) ? Am[kk + 1] : 0.0f;
        v.z = (kk + 2 < kc) ? Am[kk + 2] : 0.0f;
        v.w = (kk + 3 < kc) ? Am[kk + 3] : 0.0f;
      }
      As[m][kk + 0] = v.x; As[m][kk + 1] = v.y;
      As[m][kk + 2] = v.z; As[m][kk + 3] = v.w;
    }
  }
  __syncthreads();

  const int lane = tid & 63;
  const int n0 = __builtin_amdgcn_readfirstlane(tid >> 6) * 30;  // uniform
  float acc[30];
#pragma unroll
  for (int j = 0; j < 30; ++j) acc[j] = 0.0f;

  const float* Wb = W + k0;
  for (int kk = 0; kk < kc; ++kk) {
    const float a = As[lane][kk];
#pragma unroll
    for (int j = 0; j < 30; ++j)
      acc[j] = fmaf(a, Wb[(n0 + j) * KTOT + kk], acc[j]);  // scalar loads
  }
  float* pb = part + chunk * 7680 + n0 * 64 + lane;
#pragma unroll
  for (int j = 0; j < 30; ++j) pb[j * 64] = acc[j];
}

// ---------------- Kernel 4: reduce partials + bias + relu ------------------
__global__ __launch_bounds__(256) void fc1_reduce(
    const float* __restrict__ part, const float* __restrict__ bias,
    float* __restrict__ h1) {
  const int t = blockIdx.x * 256 + threadIdx.x;   // 0..7679, [n][m]
  const int n = t >> 6, m = t & 63;
  float s = 0.0f;
  for (int c = 0; c < NCHUNK; ++c) s += part[c * 7680 + t];
  h1[m * 120 + n] = fmaxf(s + bias[n], 0.0f);
}

// ---------------- Kernel 5: fc2 + relu -------------------------------------
// 21 blocks x 256: lane=m (64 rows), wave -> one of 4 columns j.
__global__ __launch_bounds__(256) void fc2_kernel(
    const float* __restrict__ h1, const float* __restrict__ W,
    const float* __restrict__ bias, float* __restrict__ h2) {
  __shared__ float hs[64][121];
  const int tid = threadIdx.x;
  for (int i = tid; i < 7680; i += 256) hs[i / 120][i % 120] = h1[i];
  __syncthreads();
  const int m = tid & 63;
  const int j = blockIdx.x * 4 + __builtin_amdgcn_readfirstlane(tid >> 6);
  const float* wj = W + j * 120;
  float a = bias[j];
  for (int k = 0; k < 120; ++k) a = fmaf(hs[m][k], wj[k], a);
  h2[m * 84 + j] = fmaxf(a, 0.0f);
}

// ---------------- Kernel 6: fc3 + quantum kernel head + sigmoid ------------
__global__ void final_kernel(
    const float* __restrict__ h2, const float* __restrict__ w3,
    const float* __restrict__ b3, const float* __restrict__ proto,
    const float* __restrict__ khw, const float* __restrict__ khb,
    float* __restrict__ out) {
  const int m = threadIdx.x;  // 64 lanes
  const float* h = h2 + m * 84;
  float z = b3[0];
  for (int k = 0; k < 84; ++k) z = fmaf(h[k], w3[k], z);
  float logit = khb[0];
#pragma unroll
  for (int p = 0; p < 10; ++p) {
    const float c = cosf((z - proto[p]) * 0.5f);
    const float c2 = c * c;
    logit = fmaf(c2 * c2, khw[p], logit);
  }
  const float pr = 1.0f / (1.0f + expf(-logit));
  out[m * 2 + 0] = pr;
  out[m * 2 + 1] = 1.0f - pr;
}

// ---------------------------------------------------------------------------
extern "C" void kernel_launch(void* const* d_in, const int* in_sizes, int n_in,
                              void* d_out, int out_size, void* d_ws, size_t ws_size,
                              hipStream_t stream) {
  const float* x    = (const float*)d_in[0];
  const float* w1   = (const float*)d_in[1];
  const float* b1   = (const float*)d_in[2];
  const float* w2   = (const float*)d_in[3];
  const float* b2   = (const float*)d_in[4];
  const float* fw1  = (const float*)d_in[5];
  const float* fb1  = (const float*)d_in[6];
  const float* fw2  = (const float*)d_in[7];
  const float* fb2  = (const float*)d_in[8];
  const float* fw3  = (const float*)d_in[9];
  const float* fb3  = (const float*)d_in[10];
  const float* prot = (const float*)d_in[11];
  const float* khw  = (const float*)d_in[12];
  const float* khb  = (const float*)d_in[13];
  float* out = (float*)d_out;

  float* ws = (float*)d_ws;
  // pooled1 (dead after conv2) is aliased by fc1 partials (written after).
  float* pool1 = ws;                           // 64*6*123*123 = 5,809,536 f
  float* part  = ws;                           // 437*7680     = 3,356,160 f (alias)
  float* A     = ws + 5809536;                 // 64*55815     = 3,572,160 f
  float* h1    = A + 3572160;                  // 7680 f
  float* h2    = h1 + 7680;                    // 5376 f

  conv1_pool <<<dim3(81, 64), 256, 0, stream>>>(x, w1, b1, pool1);
  conv2_pool <<<dim3(25, 64), 256, 0, stream>>>(pool1, w2, b2, A);
  fc1_partial<<<dim3(NCHUNK), 256, 0, stream>>>(A, fw1, part);
  fc1_reduce <<<dim3(30), 256, 0, stream>>>(part, fb1, h1);
  fc2_kernel <<<dim3(21), 256, 0, stream>>>(h1, fw2, fb2, h2);
  final_kernel<<<dim3(1), 64, 0, stream>>>(h2, fw3, fb3, prot, khw, khb, out);
}

// Round 2
// 193.216 us; speedup vs baseline: 1.8219x; 1.8219x over previous
//
#include <hip/hip_runtime.h>
#include <hip/hip_bf16.h>
#include <math.h>

// ---------------------------------------------------------------------------
// HybridQuantumKernelNet forward, fp32 throughout.
// x[64,3,250,250] -> conv1(6,5x5,s2,p1)+relu -> [64,6,124,124]
//   -> maxpool2 s1 -> [64,6,123,123]
//   -> conv2(15,3x3,s2,p1)+relu -> [64,15,62,62] -> maxpool2 s1 -> [64,15,61,61]
//   -> flatten K=55815 -> fc1(120)+relu -> fc2(84)+relu -> fc3(1)
//   -> quantum head cos((z-p)/2)^4 @ kh_w + kh_b -> sigmoid -> [p,1-p]
// ---------------------------------------------------------------------------

#define KTOT 55815            // 15*61*61
#define P1H 123               // pooled1 spatial
#define P2H 61                // pooled2 spatial
#define KC 96                 // fc1 K-chunk
#define NCHUNK 582            // ceil(55815/96); last chunk = 39

// ---------------- Kernel 1: conv1 + relu + maxpool(2,s1) fused -------------
__global__ __launch_bounds__(256) void conv1_pool(
    const float* __restrict__ x, const float* __restrict__ w,
    const float* __restrict__ bias, float* __restrict__ out) {
  __shared__ float cs[6][16][16];
  const int b = blockIdx.y;
  const int ty = blockIdx.x / 9, tx = blockIdx.x % 9;
  const int py0 = ty * 15, px0 = tx * 15;
  const int tid = threadIdx.x;
  const int cyl = tid >> 4, cxl = tid & 15;
  const int cy = py0 + cyl, cx = px0 + cxl;      // conv output coords
  const float* xb = x + b * 187500;              // 3*250*250
  const bool cv = (cy < 124) && (cx < 124);
  const int iy0 = 2 * cy - 1, ix0 = 2 * cx - 1;  // pad=1, stride=2

  float rin[75];
#pragma unroll
  for (int ic = 0; ic < 3; ++ic) {
    const float* xc = xb + ic * 62500;
#pragma unroll
    for (int ky = 0; ky < 5; ++ky) {
      const int iy = iy0 + ky;
#pragma unroll
      for (int kx = 0; kx < 5; ++kx) {
        const int ix = ix0 + kx;
        const bool ok = cv && (iy >= 0) && (ix >= 0);
        rin[ic * 25 + ky * 5 + kx] = ok ? xc[iy * 250 + ix] : 0.0f;
      }
    }
  }
#pragma unroll
  for (int oc = 0; oc < 6; ++oc) {
    float a = bias[oc];
#pragma unroll
    for (int i = 0; i < 75; ++i) a = fmaf(rin[i], w[oc * 75 + i], a);
    cs[oc][cyl][cxl] = fmaxf(a, 0.0f);
  }
  __syncthreads();
  if (tid < 225) {
    const int pyl = tid / 15, pxl = tid % 15;
    const int py = py0 + pyl, px = px0 + pxl;
    if (py < P1H && px < P1H) {
      float* ob = out + b * (6 * P1H * P1H);
#pragma unroll
      for (int oc = 0; oc < 6; ++oc) {
        const float v = fmaxf(fmaxf(cs[oc][pyl][pxl], cs[oc][pyl][pxl + 1]),
                              fmaxf(cs[oc][pyl + 1][pxl], cs[oc][pyl + 1][pxl + 1]));
        ob[oc * (P1H * P1H) + py * P1H + px] = v;
      }
    }
  }
}

// ---------------- Kernel 2: conv2 + relu + maxpool(2,s1) fused -------------
__global__ __launch_bounds__(256) void conv2_pool(
    const float* __restrict__ in, const float* __restrict__ w,
    const float* __restrict__ bias, float* __restrict__ A) {
  __shared__ float cs[15][16][16];
  const int b = blockIdx.y;
  const int ty = blockIdx.x / 5, tx = blockIdx.x % 5;
  const int py0 = ty * 15, px0 = tx * 15;
  const int tid = threadIdx.x;
  const int cyl = tid >> 4, cxl = tid & 15;
  const int cy = py0 + cyl, cx = px0 + cxl;
  const float* ib = in + b * (6 * P1H * P1H);
  const bool cv = (cy < 62) && (cx < 62);
  const int iy0 = 2 * cy - 1, ix0 = 2 * cx - 1;

  float rin[54];
#pragma unroll
  for (int ic = 0; ic < 6; ++ic) {
    const float* icp = ib + ic * (P1H * P1H);
#pragma unroll
    for (int ky = 0; ky < 3; ++ky) {
      const int iy = iy0 + ky;
#pragma unroll
      for (int kx = 0; kx < 3; ++kx) {
        const int ix = ix0 + kx;
        const bool ok = cv && (iy >= 0) && (iy < P1H) && (ix >= 0) && (ix < P1H);
        rin[ic * 9 + ky * 3 + kx] = ok ? icp[iy * P1H + ix] : 0.0f;
      }
    }
  }
#pragma unroll
  for (int oc = 0; oc < 15; ++oc) {
    float a = bias[oc];
#pragma unroll
    for (int i = 0; i < 54; ++i) a = fmaf(rin[i], w[oc * 54 + i], a);
    cs[oc][cyl][cxl] = fmaxf(a, 0.0f);
  }
  __syncthreads();
  if (tid < 225) {
    const int pyl = tid / 15, pxl = tid % 15;
    const int py = py0 + pyl, px = px0 + pxl;
    if (py < P2H && px < P2H) {
      float* ob = A + b * KTOT;
#pragma unroll
      for (int oc = 0; oc < 15; ++oc) {
        const float v = fmaxf(fmaxf(cs[oc][pyl][pxl], cs[oc][pyl][pxl + 1]),
                              fmaxf(cs[oc][pyl + 1][pxl], cs[oc][pyl + 1][pxl + 1]));
        ob[oc * (P2H * P2H) + py * P2H + px] = v;
      }
    }
  }
}

// ---------------- Kernel 3: fc1 split-K partials (LDS-resident) ------------
// Block = one K-chunk of 96, all 120 n, all 64 m. A chunk in LDS [64][97]
// (pad 1 -> column reads bank (m+k)%32 conflict-free). W chunk in LDS
// [120][96] flat (rows 384B -> 16B-aligned float4, wave-uniform ds_read_b128
// broadcast). Lanes = m, wave handles 30 n's; acc in regs; no cross-lane
// reduce. Inner loop is pure LDS+VALU -> VALU-bound.
__global__ __launch_bounds__(256) void fc1_partial(
    const float* __restrict__ A, const float* __restrict__ W,
    float* __restrict__ part) {
  __shared__ float As[64 * 97];
  __shared__ float Ws[120 * KC];
  const int tid = threadIdx.x;
  const int chunk = blockIdx.x;
  const int k0 = chunk * KC;
  const int kc = min(KC, KTOT - k0);

  for (int idx = tid; idx < 64 * KC; idx += 256) {
    const int m = idx / KC, kk = idx - m * KC;
    As[m * 97 + kk] = (kk < kc) ? A[m * KTOT + k0 + kk] : 0.0f;
  }
  for (int idx = tid; idx < 120 * KC; idx += 256) {
    const int n = idx / KC, kk = idx - n * KC;
    Ws[idx] = (kk < kc) ? W[n * KTOT + k0 + kk] : 0.0f;
  }
  __syncthreads();

  const int lane = tid & 63;
  const int n0 = __builtin_amdgcn_readfirstlane(tid >> 6) * 30;  // uniform
  float acc[30];
#pragma unroll
  for (int j = 0; j < 30; ++j) acc[j] = 0.0f;

  const float* Ap = As + lane * 97;
  for (int k4 = 0; k4 < KC / 4; ++k4) {
    const float a0 = Ap[4 * k4 + 0];
    const float a1 = Ap[4 * k4 + 1];
    const float a2 = Ap[4 * k4 + 2];
    const float a3 = Ap[4 * k4 + 3];
#pragma unroll
    for (int j = 0; j < 30; ++j) {
      const float4 w = *reinterpret_cast<const float4*>(&Ws[(n0 + j) * KC + 4 * k4]);
      float a = acc[j];
      a = fmaf(a0, w.x, a);
      a = fmaf(a1, w.y, a);
      a = fmaf(a2, w.z, a);
      a = fmaf(a3, w.w, a);
      acc[j] = a;
    }
  }
  float* pb = part + chunk * 7680 + n0 * 64 + lane;
#pragma unroll
  for (int j = 0; j < 30; ++j) pb[j * 64] = acc[j];
}

// ---------------- Kernel 4: reduce partials + bias + relu ------------------
// One block per n (120 blocks); 4-way chunk split per block, LDS combine.
__global__ __launch_bounds__(256) void fc1_reduce(
    const float* __restrict__ part, const float* __restrict__ bias,
    float* __restrict__ h1) {
  __shared__ float red[4][64];
  const int n = blockIdx.x;
  const int tid = threadIdx.x;
  const int m = tid & 63, q = tid >> 6;
  float s = 0.0f;
  for (int c = q; c < NCHUNK; c += 4) s += part[c * 7680 + n * 64 + m];
  red[q][m] = s;
  __syncthreads();
  if (q == 0) {
    const float t = red[0][m] + red[1][m] + red[2][m] + red[3][m];
    h1[m * 120 + n] = fmaxf(t + bias[n], 0.0f);
  }
}

// ---------------- Kernel 5: fc2 + relu -------------------------------------
__global__ __launch_bounds__(256) void fc2_kernel(
    const float* __restrict__ h1, const float* __restrict__ W,
    const float* __restrict__ bias, float* __restrict__ h2) {
  __shared__ float hs[64][121];
  const int tid = threadIdx.x;
  for (int i = tid; i < 7680; i += 256) hs[i / 120][i % 120] = h1[i];
  __syncthreads();
  const int m = tid & 63;
  const int j = blockIdx.x * 4 + __builtin_amdgcn_readfirstlane(tid >> 6);
  const float* wj = W + j * 120;
  float a = bias[j];
  for (int k = 0; k < 120; ++k) a = fmaf(hs[m][k], wj[k], a);
  h2[m * 84 + j] = fmaxf(a, 0.0f);
}

// ---------------- Kernel 6: fc3 + quantum kernel head + sigmoid ------------
__global__ void final_kernel(
    const float* __restrict__ h2, const float* __restrict__ w3,
    const float* __restrict__ b3, const float* __restrict__ proto,
    const float* __restrict__ khw, const float* __restrict__ khb,
    float* __restrict__ out) {
  const int m = threadIdx.x;  // 64 lanes
  const float* h = h2 + m * 84;
  float z = b3[0];
  for (int k = 0; k < 84; ++k) z = fmaf(h[k], w3[k], z);
  float logit = khb[0];
#pragma unroll
  for (int p = 0; p < 10; ++p) {
    const float c = cosf((z - proto[p]) * 0.5f);
    const float c2 = c * c;
    logit = fmaf(c2 * c2, khw[p], logit);
  }
  const float pr = 1.0f / (1.0f + expf(-logit));
  out[m * 2 + 0] = pr;
  out[m * 2 + 1] = 1.0f - pr;
}

// ---------------------------------------------------------------------------
extern "C" void kernel_launch(void* const* d_in, const int* in_sizes, int n_in,
                              void* d_out, int out_size, void* d_ws, size_t ws_size,
                              hipStream_t stream) {
  const float* x    = (const float*)d_in[0];
  const float* w1   = (const float*)d_in[1];
  const float* b1   = (const float*)d_in[2];
  const float* w2   = (const float*)d_in[3];
  const float* b2   = (const float*)d_in[4];
  const float* fw1  = (const float*)d_in[5];
  const float* fb1  = (const float*)d_in[6];
  const float* fw2  = (const float*)d_in[7];
  const float* fb2  = (const float*)d_in[8];
  const float* fw3  = (const float*)d_in[9];
  const float* fb3  = (const float*)d_in[10];
  const float* prot = (const float*)d_in[11];
  const float* khw  = (const float*)d_in[12];
  const float* khb  = (const float*)d_in[13];
  float* out = (float*)d_out;

  float* ws = (float*)d_ws;
  // pool1 (dead after conv2) is aliased by fc1 partials (written after).
  float* pool1 = ws;                           // 64*6*123*123 = 5,809,536 f
  float* part  = ws;                           // 582*7680     = 4,469,760 f (alias)
  float* A     = ws + 5809536;                 // 64*55815     = 3,572,160 f
  float* h1    = A + 3572160;                  // 7680 f
  float* h2    = h1 + 7680;                    // 5376 f

  conv1_pool <<<dim3(81, 64), 256, 0, stream>>>(x, w1, b1, pool1);
  conv2_pool <<<dim3(25, 64), 256, 0, stream>>>(pool1, w2, b2, A);
  fc1_partial<<<dim3(NCHUNK), 256, 0, stream>>>(A, fw1, part);
  fc1_reduce <<<dim3(120), 256, 0, stream>>>(part, fb1, h1);
  fc2_kernel <<<dim3(21), 256, 0, stream>>>(h1, fw2, fb2, h2);
  final_kernel<<<dim3(1), 64, 0, stream>>>(h2, fw3, fb3, prot, khw, khb, out);
}

// Round 3
// 165.757 us; speedup vs baseline: 2.1237x; 1.1657x over previous
//
#include <hip/hip_runtime.h>
#include <hip/hip_bf16.h>
#include <math.h>

// ---------------------------------------------------------------------------
// HybridQuantumKernelNet forward, fp32 throughout.
// x[64,3,250,250] -> conv1(6,5x5,s2,p1)+relu -> [64,6,124,124]
//   -> maxpool2 s1 -> [64,6,123,123]
//   -> conv2(15,3x3,s2,p1)+relu -> [64,15,62,62] -> maxpool2 s1 -> [64,15,61,61]
//   -> flatten K=55815 -> fc1(120)+relu -> fc2(84)+relu -> fc3(1)
//   -> quantum head cos((z-p)/2)^4 @ kh_w + kh_b -> sigmoid -> [p,1-p]
// ---------------------------------------------------------------------------

#define KTOT 55815            // 15*61*61
#define KTOT_PAD 55872        // 582*96 : A row stride (57-float zero pad)
#define P1H 123               // pooled1 spatial
#define P2H 61                // pooled2 spatial
#define KC 96                 // fc1 K-chunk
#define NCHUNK 582            // KTOT_PAD / KC

// ---------------- Kernel 0: zero A row padding -----------------------------
__global__ void zero_pad_A(float* __restrict__ A) {
  const int i = blockIdx.x * 256 + threadIdx.x;  // 64*57 = 3648
  if (i < 64 * 57) {
    const int b = i / 57, j = i % 57;
    A[(size_t)b * KTOT_PAD + KTOT + j] = 0.0f;
  }
}

// ---------------- Kernel 1: conv1 + relu + maxpool(2,s1) fused -------------
__global__ __launch_bounds__(256) void conv1_pool(
    const float* __restrict__ x, const float* __restrict__ w,
    const float* __restrict__ bias, float* __restrict__ out) {
  __shared__ float cs[6][16][16];
  const int b = blockIdx.y;
  const int ty = blockIdx.x / 9, tx = blockIdx.x % 9;
  const int py0 = ty * 15, px0 = tx * 15;
  const int tid = threadIdx.x;
  const int cyl = tid >> 4, cxl = tid & 15;
  const int cy = py0 + cyl, cx = px0 + cxl;      // conv output coords
  const float* xb = x + b * 187500;              // 3*250*250
  const bool cv = (cy < 124) && (cx < 124);
  const int iy0 = 2 * cy - 1, ix0 = 2 * cx - 1;  // pad=1, stride=2

  float rin[75];
#pragma unroll
  for (int ic = 0; ic < 3; ++ic) {
    const float* xc = xb + ic * 62500;
#pragma unroll
    for (int ky = 0; ky < 5; ++ky) {
      const int iy = iy0 + ky;
#pragma unroll
      for (int kx = 0; kx < 5; ++kx) {
        const int ix = ix0 + kx;
        const bool ok = cv && (iy >= 0) && (ix >= 0);
        rin[ic * 25 + ky * 5 + kx] = ok ? xc[iy * 250 + ix] : 0.0f;
      }
    }
  }
#pragma unroll
  for (int oc = 0; oc < 6; ++oc) {
    float a = bias[oc];
#pragma unroll
    for (int i = 0; i < 75; ++i) a = fmaf(rin[i], w[oc * 75 + i], a);
    cs[oc][cyl][cxl] = fmaxf(a, 0.0f);
  }
  __syncthreads();
  if (tid < 225) {
    const int pyl = tid / 15, pxl = tid % 15;
    const int py = py0 + pyl, px = px0 + pxl;
    if (py < P1H && px < P1H) {
      float* ob = out + b * (6 * P1H * P1H);
#pragma unroll
      for (int oc = 0; oc < 6; ++oc) {
        const float v = fmaxf(fmaxf(cs[oc][pyl][pxl], cs[oc][pyl][pxl + 1]),
                              fmaxf(cs[oc][pyl + 1][pxl], cs[oc][pyl + 1][pxl + 1]));
        ob[oc * (P1H * P1H) + py * P1H + px] = v;
      }
    }
  }
}

// ---------------- Kernel 2: conv2 + relu + maxpool(2,s1) fused -------------
// Output A rows use stride KTOT_PAD (zero-padded tail) so fc1 staging can
// use aligned float4 loads unconditionally.
__global__ __launch_bounds__(256) void conv2_pool(
    const float* __restrict__ in, const float* __restrict__ w,
    const float* __restrict__ bias, float* __restrict__ A) {
  __shared__ float cs[15][16][16];
  const int b = blockIdx.y;
  const int ty = blockIdx.x / 5, tx = blockIdx.x % 5;
  const int py0 = ty * 15, px0 = tx * 15;
  const int tid = threadIdx.x;
  const int cyl = tid >> 4, cxl = tid & 15;
  const int cy = py0 + cyl, cx = px0 + cxl;
  const float* ib = in + b * (6 * P1H * P1H);
  const bool cv = (cy < 62) && (cx < 62);
  const int iy0 = 2 * cy - 1, ix0 = 2 * cx - 1;

  float rin[54];
#pragma unroll
  for (int ic = 0; ic < 6; ++ic) {
    const float* icp = ib + ic * (P1H * P1H);
#pragma unroll
    for (int ky = 0; ky < 3; ++ky) {
      const int iy = iy0 + ky;
#pragma unroll
      for (int kx = 0; kx < 3; ++kx) {
        const int ix = ix0 + kx;
        const bool ok = cv && (iy >= 0) && (iy < P1H) && (ix >= 0) && (ix < P1H);
        rin[ic * 9 + ky * 3 + kx] = ok ? icp[iy * P1H + ix] : 0.0f;
      }
    }
  }
#pragma unroll
  for (int oc = 0; oc < 15; ++oc) {
    float a = bias[oc];
#pragma unroll
    for (int i = 0; i < 54; ++i) a = fmaf(rin[i], w[oc * 54 + i], a);
    cs[oc][cyl][cxl] = fmaxf(a, 0.0f);
  }
  __syncthreads();
  if (tid < 225) {
    const int pyl = tid / 15, pxl = tid % 15;
    const int py = py0 + pyl, px = px0 + pxl;
    if (py < P2H && px < P2H) {
      float* ob = A + (size_t)b * KTOT_PAD;
#pragma unroll
      for (int oc = 0; oc < 15; ++oc) {
        const float v = fmaxf(fmaxf(cs[oc][pyl][pxl], cs[oc][pyl][pxl + 1]),
                              fmaxf(cs[oc][pyl + 1][pxl], cs[oc][pyl + 1][pxl + 1]));
        ob[oc * (P2H * P2H) + py * P2H + px] = v;
      }
    }
  }
}

// ---------------- Kernel 3: fc1 split-K partials, register-tiled -----------
// Block = K-chunk of 96, full 64m x 128n(120 real). 4 waves split n (32 each).
// Lane grid 8mg x 8ng; per-lane tile 8m x 4n. Per k4-step: 8 A-b128 + 4
// W-b128 (XOR-swizzled slots -> 8 disjoint 4-bank spans, conflict-free,
// broadcast-8) feed 128 FMAs. LDS rows are exactly 96 floats; element
// (row,k) lives at row*96 + 4*((k4&24)|((k4&7)^key)) + (k&3),
// key = (m>>3)&7 for A, (n>>2)&7 for W.
__global__ __launch_bounds__(256) void fc1_partial(
    const float* __restrict__ A, const float* __restrict__ W,
    float* __restrict__ part) {
  __shared__ float As[64 * KC];
  __shared__ float Ws[128 * KC];
  const int tid = threadIdx.x;
  const int chunk = blockIdx.x;
  const int k0 = chunk * KC;

  // Stage A: unconditional aligned float4 (A rows padded+zeroed).
  for (int idx = tid; idx < 64 * 24; idx += 256) {
    const int m = idx / 24, j = idx % 24;   // j = k4
    const float4 v = *reinterpret_cast<const float4*>(
        A + (size_t)m * KTOT_PAD + k0 + 4 * j);
    const int slot = (j & 24) | ((j & 7) ^ ((m >> 3) & 7));
    *reinterpret_cast<float4*>(&As[m * KC + 4 * slot]) = v;
  }
  // Stage W scalar-coalesced; tail chunk masked (uniform branch).
  if (k0 + KC <= KTOT) {
    for (int idx = tid; idx < 120 * KC; idx += 256) {
      const int n = idx / KC, k = idx - n * KC;
      const int j = k >> 2, q = k & 3;
      const int slot = (j & 24) | ((j & 7) ^ ((n >> 2) & 7));
      Ws[n * KC + 4 * slot + q] = W[(size_t)n * KTOT + k0 + k];
    }
  } else {
    for (int idx = tid; idx < 120 * KC; idx += 256) {
      const int n = idx / KC, k = idx - n * KC;
      const int j = k >> 2, q = k & 3;
      const int slot = (j & 24) | ((j & 7) ^ ((n >> 2) & 7));
      const int kg = k0 + k;
      Ws[n * KC + 4 * slot + q] = (kg < KTOT) ? W[(size_t)n * KTOT + kg] : 0.0f;
    }
  }
  __syncthreads();

  const int lane = tid & 63;
  const int wave = __builtin_amdgcn_readfirstlane(tid >> 6);
  const int mg = lane >> 3, ng = lane & 7;
  const int n0 = wave * 32;
  const float* Abase = As + mg * 8 * KC;
  const float* Wbase = Ws + (n0 + ng * 4) * KC;

  float acc[8][4];
#pragma unroll
  for (int r = 0; r < 8; ++r)
#pragma unroll
    for (int s = 0; s < 4; ++s) acc[r][s] = 0.0f;

  for (int k4 = 0; k4 < KC / 4; ++k4) {
    const int sA = 4 * ((k4 & 24) | ((k4 & 7) ^ mg));
    const int sW = 4 * ((k4 & 24) | ((k4 & 7) ^ ng));
    float4 a[8], w[4];
#pragma unroll
    for (int r = 0; r < 8; ++r)
      a[r] = *reinterpret_cast<const float4*>(Abase + r * KC + sA);
#pragma unroll
    for (int s = 0; s < 4; ++s)
      w[s] = *reinterpret_cast<const float4*>(Wbase + s * KC + sW);
#pragma unroll
    for (int r = 0; r < 8; ++r)
#pragma unroll
      for (int s = 0; s < 4; ++s) {
        float t = acc[r][s];
        t = fmaf(a[r].x, w[s].x, t);
        t = fmaf(a[r].y, w[s].y, t);
        t = fmaf(a[r].z, w[s].z, t);
        t = fmaf(a[r].w, w[s].w, t);
        acc[r][s] = t;
      }
  }

  // Store partials [chunk][m][n] as float4 over n; mask the n>=120 pad.
  if (n0 + 4 * ng <= 116) {
    float* pb = part + (size_t)chunk * 7680 + n0 + 4 * ng;
#pragma unroll
    for (int r = 0; r < 8; ++r) {
      const float4 v = {acc[r][0], acc[r][1], acc[r][2], acc[r][3]};
      *reinterpret_cast<float4*>(pb + (mg * 8 + r) * 120) = v;
    }
  }
}

// ---------------- Kernel 4: reduce partials + bias + relu ------------------
// 120 blocks x 256: block covers 64 t's, 4-way chunk split, LDS combine.
// part layout [chunk][m][n], t = m*120+n; h1[t] matches fc2's read order.
__global__ __launch_bounds__(256) void fc1_reduce(
    const float* __restrict__ part, const float* __restrict__ bias,
    float* __restrict__ h1) {
  __shared__ float red[4][64];
  const int tid = threadIdx.x;
  const int q = tid >> 6, l = tid & 63;
  const int t = blockIdx.x * 64 + l;   // 120*64 = 7680
  float s = 0.0f;
  for (int c = q; c < NCHUNK; c += 4) s += part[(size_t)c * 7680 + t];
  red[q][l] = s;
  __syncthreads();
  if (q == 0) {
    const int n = t % 120;
    const float v = red[0][l] + red[1][l] + red[2][l] + red[3][l] + bias[n];
    h1[t] = fmaxf(v, 0.0f);
  }
}

// ---------------- Kernel 5: fc2 + relu -------------------------------------
__global__ __launch_bounds__(256) void fc2_kernel(
    const float* __restrict__ h1, const float* __restrict__ W,
    const float* __restrict__ bias, float* __restrict__ h2) {
  __shared__ float hs[64][121];
  const int tid = threadIdx.x;
  for (int i = tid; i < 7680; i += 256) hs[i / 120][i % 120] = h1[i];
  __syncthreads();
  const int m = tid & 63;
  const int j = blockIdx.x * 4 + __builtin_amdgcn_readfirstlane(tid >> 6);
  const float* wj = W + j * 120;
  float a = bias[j];
  for (int k = 0; k < 120; ++k) a = fmaf(hs[m][k], wj[k], a);
  h2[m * 84 + j] = fmaxf(a, 0.0f);
}

// ---------------- Kernel 6: fc3 + quantum kernel head + sigmoid ------------
__global__ void final_kernel(
    const float* __restrict__ h2, const float* __restrict__ w3,
    const float* __restrict__ b3, const float* __restrict__ proto,
    const float* __restrict__ khw, const float* __restrict__ khb,
    float* __restrict__ out) {
  const int m = threadIdx.x;  // 64 lanes
  const float* h = h2 + m * 84;
  float z = b3[0];
  for (int k = 0; k < 84; ++k) z = fmaf(h[k], w3[k], z);
  float logit = khb[0];
#pragma unroll
  for (int p = 0; p < 10; ++p) {
    const float c = cosf((z - proto[p]) * 0.5f);
    const float c2 = c * c;
    logit = fmaf(c2 * c2, khw[p], logit);
  }
  const float pr = 1.0f / (1.0f + expf(-logit));
  out[m * 2 + 0] = pr;
  out[m * 2 + 1] = 1.0f - pr;
}

// ---------------------------------------------------------------------------
extern "C" void kernel_launch(void* const* d_in, const int* in_sizes, int n_in,
                              void* d_out, int out_size, void* d_ws, size_t ws_size,
                              hipStream_t stream) {
  const float* x    = (const float*)d_in[0];
  const float* w1   = (const float*)d_in[1];
  const float* b1   = (const float*)d_in[2];
  const float* w2   = (const float*)d_in[3];
  const float* b2   = (const float*)d_in[4];
  const float* fw1  = (const float*)d_in[5];
  const float* fb1  = (const float*)d_in[6];
  const float* fw2  = (const float*)d_in[7];
  const float* fb2  = (const float*)d_in[8];
  const float* fw3  = (const float*)d_in[9];
  const float* fb3  = (const float*)d_in[10];
  const float* prot = (const float*)d_in[11];
  const float* khw  = (const float*)d_in[12];
  const float* khb  = (const float*)d_in[13];
  float* out = (float*)d_out;

  float* ws = (float*)d_ws;
  // pool1 (dead after conv2) is aliased by fc1 partials (written after).
  float* pool1 = ws;                           // 64*6*123*123 = 5,809,536 f
  float* part  = ws;                           // 582*7680     = 4,469,760 f (alias)
  float* A     = ws + 5809536;                 // 64*55872     = 3,575,808 f
  float* h1    = A + 3575808;                  // 7680 f
  float* h2    = h1 + 7680;                    // 5376 f

  zero_pad_A <<<dim3(15), 256, 0, stream>>>(A);
  conv1_pool <<<dim3(81, 64), 256, 0, stream>>>(x, w1, b1, pool1);
  conv2_pool <<<dim3(25, 64), 256, 0, stream>>>(pool1, w2, b2, A);
  fc1_partial<<<dim3(NCHUNK), 256, 0, stream>>>(A, fw1, part);
  fc1_reduce <<<dim3(120), 256, 0, stream>>>(part, fb1, h1);
  fc2_kernel <<<dim3(21), 256, 0, stream>>>(h1, fw2, fb2, h2);
  final_kernel<<<dim3(1), 64, 0, stream>>>(h2, fw3, fb3, prot, khw, khb, out);
}

// Round 4
// 148.494 us; speedup vs baseline: 2.3706x; 1.1163x over previous
//
#include <hip/hip_runtime.h>
#include <hip/hip_bf16.h>
#include <math.h>

// ---------------------------------------------------------------------------
// HybridQuantumKernelNet forward, fp32 throughout.
// x[64,3,250,250] -> conv1(6,5x5,s2,p1)+relu -> [64,6,124,124]
//   -> maxpool2 s1 -> pool1 [64,123,123,6] (CHANNEL-LAST)
//   -> conv2(15,3x3,s2,p1)+relu -> [64,15,62,62] -> maxpool2 s1 -> [64,15,61,61]
//   -> flatten K=55815 -> fc1(120)+relu -> fc2(84)+relu -> fc3(1)
//   -> quantum head cos((z-p)/2)^4 @ kh_w + kh_b -> sigmoid -> [p,1-p]
// ---------------------------------------------------------------------------

#define KTOT 55815            // 15*61*61
#define KTOT_PAD 55872        // A row stride (alignment only; tail guarded)
#define P1H 123               // pooled1 spatial
#define P2H 61                // pooled2 spatial
#define KC 96                 // fc1 K-chunk
#define NCHUNK 582            // ceil(55815/96)

// ---------------- Kernel 1: conv1 + relu + maxpool(2,s1), channel-last -----
// Thread: 8 consecutive conv cols (x-strip), all 6 oc. Tile: 32 conv rows x
// 64 conv cols (row stride 31, col bases {0,62} -> 1-overlap for pool).
// Even col base => per-row 24-float window starts at multiple of 4 => 6
// aligned float4 loads, taps at r[2p+3+kx] (compile-time indices).
__global__ __launch_bounds__(256) void conv1_pool(
    const float* __restrict__ x, const float* __restrict__ w,
    const float* __restrict__ bias, float* __restrict__ out) {
  __shared__ float cs[6][32][65];                // 49,920 B; 65 => 2-way banks
  const int b = blockIdx.y;
  const int ytile = blockIdx.x >> 1, xtile = blockIdx.x & 1;
  const int cy_base = 31 * ytile;                // conv row base (overlap 1)
  const int cx_base = xtile ? 62 : 0;            // conv col base (EVEN)
  const int tid = threadIdx.x;
  const int ry = tid >> 3;                       // 0..31 local conv row
  const int tx8 = tid & 7;                       // 8-col strip index
  const int cy = cy_base + ry;
  const int cx0 = cx_base + 8 * tx8;
  const int w0 = 2 * cx0 - 4;                    // window start, mult of 4
  const float* xb = x + b * 187500;

  float acc[6][8];
#pragma unroll
  for (int oc = 0; oc < 6; ++oc) {
    const float bv = bias[oc];
#pragma unroll
    for (int p = 0; p < 8; ++p) acc[oc][p] = bv;
  }

  const bool cyv = (cy < 124);
#pragma unroll
  for (int ic = 0; ic < 3; ++ic) {
    const float* xc = xb + ic * 62500;
#pragma unroll
    for (int ky = 0; ky < 5; ++ky) {
      const int iy = 2 * cy - 1 + ky;
      const bool vrow = cyv && (iy >= 0) && (iy < 250);
      const float* rp = xc + iy * 250;
      float r[24];
#pragma unroll
      for (int j = 0; j < 6; ++j) {
        const int s = w0 + 4 * j;
        float4 v = {0.f, 0.f, 0.f, 0.f};
        if (vrow) {
          if (s >= 0 && s + 3 < 250) {
            v = *reinterpret_cast<const float4*>(rp + s);
          } else if (s + 3 >= 0 && s < 250) {     // partial edge f4
            v.x = (s + 0 >= 0 && s + 0 < 250) ? rp[s + 0] : 0.f;
            v.y = (s + 1 >= 0 && s + 1 < 250) ? rp[s + 1] : 0.f;
            v.z = (s + 2 >= 0 && s + 2 < 250) ? rp[s + 2] : 0.f;
            v.w = (s + 3 >= 0 && s + 3 < 250) ? rp[s + 3] : 0.f;
          }
        }
        r[4 * j + 0] = v.x; r[4 * j + 1] = v.y;
        r[4 * j + 2] = v.z; r[4 * j + 3] = v.w;
      }
      const float* wp = w + ic * 25 + ky * 5;
#pragma unroll
      for (int oc = 0; oc < 6; ++oc)
#pragma unroll
        for (int kx = 0; kx < 5; ++kx) {
          const float wv = wp[oc * 75 + kx];     // wave-uniform (s_load)
#pragma unroll
          for (int p = 0; p < 8; ++p)
            acc[oc][p] = fmaf(r[2 * p + 3 + kx], wv, acc[oc][p]);
        }
    }
  }

#pragma unroll
  for (int oc = 0; oc < 6; ++oc)
#pragma unroll
    for (int p = 0; p < 8; ++p)
      cs[oc][ry][8 * tx8 + p] = fmaxf(acc[oc][p], 0.f);
  __syncthreads();

  // Pool phase: 31x63 pooled positions per tile, channel-last stores.
  const int py0 = cy_base;
  for (int idx = tid; idx < 31 * 63; idx += 256) {
    const int pyl = idx / 63, pxl = idx % 63;
    const int py = py0 + pyl;
    const int px = cx_base + pxl;
    if (py > 122) continue;
    if (xtile == 1 && (pxl == 0 || px > 122)) continue;
    float* ob = out + ((size_t)(b * P1H + py) * P1H + px) * 6;
    float v[6];
#pragma unroll
    for (int oc = 0; oc < 6; ++oc)
      v[oc] = fmaxf(fmaxf(cs[oc][pyl][pxl],     cs[oc][pyl][pxl + 1]),
                    fmaxf(cs[oc][pyl + 1][pxl], cs[oc][pyl + 1][pxl + 1]));
    float2 o0 = {v[0], v[1]}, o1 = {v[2], v[3]}, o2 = {v[4], v[5]};
    *reinterpret_cast<float2*>(ob + 0) = o0;
    *reinterpret_cast<float2*>(ob + 2) = o1;
    *reinterpret_cast<float2*>(ob + 4) = o2;
  }
}

// ---------------- Kernel 2: conv2 + relu + maxpool(2,s1) fused -------------
// Input channel-last [b][123][123][6]: per tap 6 contiguous floats = 3 f2.
// Output A rows use stride KTOT_PAD (tail handled by fc1 staging guard).
__global__ __launch_bounds__(256) void conv2_pool(
    const float* __restrict__ in, const float* __restrict__ w,
    const float* __restrict__ bias, float* __restrict__ A) {
  __shared__ float cs[15][16][16];
  const int b = blockIdx.y;
  const int ty = blockIdx.x / 5, tx = blockIdx.x % 5;
  const int py0 = ty * 15, px0 = tx * 15;
  const int tid = threadIdx.x;
  const int cyl = tid >> 4, cxl = tid & 15;
  const int cy = py0 + cyl, cx = px0 + cxl;
  const float* ib = in + (size_t)b * (P1H * P1H * 6);
  const bool cv = (cy < 62) && (cx < 62);
  const int iy0 = 2 * cy - 1, ix0 = 2 * cx - 1;

  float rin[54];                                  // layout [ky][kx][ic]
#pragma unroll
  for (int ky = 0; ky < 3; ++ky) {
    const int iy = iy0 + ky;
#pragma unroll
    for (int kx = 0; kx < 3; ++kx) {
      const int ix = ix0 + kx;
      const int e = (ky * 3 + kx) * 6;
      const bool ok = cv && (iy >= 0) && (iy < P1H) && (ix >= 0) && (ix < P1H);
      if (ok) {
        const float* p = ib + ((size_t)iy * P1H + ix) * 6;
        const float2 v0 = *reinterpret_cast<const float2*>(p + 0);
        const float2 v1 = *reinterpret_cast<const float2*>(p + 2);
        const float2 v2 = *reinterpret_cast<const float2*>(p + 4);
        rin[e + 0] = v0.x; rin[e + 1] = v0.y; rin[e + 2] = v1.x;
        rin[e + 3] = v1.y; rin[e + 4] = v2.x; rin[e + 5] = v2.y;
      } else {
        rin[e + 0] = 0.f; rin[e + 1] = 0.f; rin[e + 2] = 0.f;
        rin[e + 3] = 0.f; rin[e + 4] = 0.f; rin[e + 5] = 0.f;
      }
    }
  }
#pragma unroll
  for (int oc = 0; oc < 15; ++oc) {
    float a = bias[oc];
#pragma unroll
    for (int ic = 0; ic < 6; ++ic)
#pragma unroll
      for (int ky = 0; ky < 3; ++ky)
#pragma unroll
        for (int kx = 0; kx < 3; ++kx)
          a = fmaf(rin[(ky * 3 + kx) * 6 + ic],
                   w[oc * 54 + ic * 9 + ky * 3 + kx], a);
    cs[oc][cyl][cxl] = fmaxf(a, 0.f);
  }
  __syncthreads();
  if (tid < 225) {
    const int pyl = tid / 15, pxl = tid % 15;
    const int py = py0 + pyl, px = px0 + pxl;
    if (py < P2H && px < P2H) {
      float* ob = A + (size_t)b * KTOT_PAD;
#pragma unroll
      for (int oc = 0; oc < 15; ++oc) {
        const float v = fmaxf(fmaxf(cs[oc][pyl][pxl], cs[oc][pyl][pxl + 1]),
                              fmaxf(cs[oc][pyl + 1][pxl], cs[oc][pyl + 1][pxl + 1]));
        ob[oc * (P2H * P2H) + py * P2H + px] = v;
      }
    }
  }
}

// ---------------- Kernel 3: fc1 split-K partials, register-tiled -----------
// Block = K-chunk of 96, full 64m x 128n(120 real). 4 waves split n (32 each).
// Lane grid 8mg x 8ng; per-lane tile 8m x 4n. Per k4-step: 8 A-b128 + 4
// W-b128 (XOR-swizzled slots -> conflict-free) feed 128 FMAs.
__global__ __launch_bounds__(256) void fc1_partial(
    const float* __restrict__ A, const float* __restrict__ W,
    float* __restrict__ part) {
  __shared__ float As[64 * KC];
  __shared__ float Ws[128 * KC];
  const int tid = threadIdx.x;
  const int chunk = blockIdx.x;
  const int k0 = chunk * KC;
  const bool full = (k0 + KC <= KTOT);

  for (int idx = tid; idx < 64 * 24; idx += 256) {
    const int m = idx / 24, j = idx % 24;
    const int kg = k0 + 4 * j;
    float4 v;
    if (full || kg + 3 < KTOT) {
      v = *reinterpret_cast<const float4*>(A + (size_t)m * KTOT_PAD + kg);
    } else {
      v.x = (kg + 0 < KTOT) ? A[(size_t)m * KTOT_PAD + kg + 0] : 0.f;
      v.y = (kg + 1 < KTOT) ? A[(size_t)m * KTOT_PAD + kg + 1] : 0.f;
      v.z = (kg + 2 < KTOT) ? A[(size_t)m * KTOT_PAD + kg + 2] : 0.f;
      v.w = (kg + 3 < KTOT) ? A[(size_t)m * KTOT_PAD + kg + 3] : 0.f;
    }
    const int slot = (j & 24) | ((j & 7) ^ ((m >> 3) & 7));
    *reinterpret_cast<float4*>(&As[m * KC + 4 * slot]) = v;
  }
  if (full) {
    for (int idx = tid; idx < 120 * KC; idx += 256) {
      const int n = idx / KC, k = idx - n * KC;
      const int j = k >> 2, q = k & 3;
      const int slot = (j & 24) | ((j & 7) ^ ((n >> 2) & 7));
      Ws[n * KC + 4 * slot + q] = W[(size_t)n * KTOT + k0 + k];
    }
  } else {
    for (int idx = tid; idx < 120 * KC; idx += 256) {
      const int n = idx / KC, k = idx - n * KC;
      const int j = k >> 2, q = k & 3;
      const int slot = (j & 24) | ((j & 7) ^ ((n >> 2) & 7));
      const int kg = k0 + k;
      Ws[n * KC + 4 * slot + q] = (kg < KTOT) ? W[(size_t)n * KTOT + kg] : 0.f;
    }
  }
  __syncthreads();

  const int lane = tid & 63;
  const int wave = __builtin_amdgcn_readfirstlane(tid >> 6);
  const int mg = lane >> 3, ng = lane & 7;
  const int n0 = wave * 32;
  const float* Abase = As + mg * 8 * KC;
  const float* Wbase = Ws + (n0 + ng * 4) * KC;

  float acc[8][4];
#pragma unroll
  for (int r = 0; r < 8; ++r)
#pragma unroll
    for (int s = 0; s < 4; ++s) acc[r][s] = 0.0f;

  for (int k4 = 0; k4 < KC / 4; ++k4) {
    const int sA = 4 * ((k4 & 24) | ((k4 & 7) ^ mg));
    const int sW = 4 * ((k4 & 24) | ((k4 & 7) ^ ng));
    float4 a[8], w[4];
#pragma unroll
    for (int r = 0; r < 8; ++r)
      a[r] = *reinterpret_cast<const float4*>(Abase + r * KC + sA);
#pragma unroll
    for (int s = 0; s < 4; ++s)
      w[s] = *reinterpret_cast<const float4*>(Wbase + s * KC + sW);
#pragma unroll
    for (int r = 0; r < 8; ++r)
#pragma unroll
      for (int s = 0; s < 4; ++s) {
        float t = acc[r][s];
        t = fmaf(a[r].x, w[s].x, t);
        t = fmaf(a[r].y, w[s].y, t);
        t = fmaf(a[r].z, w[s].z, t);
        t = fmaf(a[r].w, w[s].w, t);
        acc[r][s] = t;
      }
  }

  if (n0 + 4 * ng <= 116) {
    float* pb = part + (size_t)chunk * 7680 + n0 + 4 * ng;
#pragma unroll
    for (int r = 0; r < 8; ++r) {
      const float4 v = {acc[r][0], acc[r][1], acc[r][2], acc[r][3]};
      *reinterpret_cast<float4*>(pb + (mg * 8 + r) * 120) = v;
    }
  }
}

// ---------------- Kernel 4: reduce partials + bias + relu ------------------
// 240 blocks x 256: 32 t's per block, 8-way chunk split, LDS combine.
__global__ __launch_bounds__(256) void fc1_reduce(
    const float* __restrict__ part, const float* __restrict__ bias,
    float* __restrict__ h1) {
  __shared__ float red[8][32];
  const int tid = threadIdx.x;
  const int q = tid >> 5, l = tid & 31;
  const int t = blockIdx.x * 32 + l;   // 240*32 = 7680
  float s = 0.0f;
  for (int c = q; c < NCHUNK; c += 8) s += part[(size_t)c * 7680 + t];
  red[q][l] = s;
  __syncthreads();
  if (q == 0) {
    float v = red[0][l] + red[1][l] + red[2][l] + red[3][l] +
              red[4][l] + red[5][l] + red[6][l] + red[7][l] + bias[t % 120];
    h1[t] = fmaxf(v, 0.0f);
  }
}

// ---------------- Kernel 5: fc2 + relu -------------------------------------
__global__ __launch_bounds__(256) void fc2_kernel(
    const float* __restrict__ h1, const float* __restrict__ W,
    const float* __restrict__ bias, float* __restrict__ h2) {
  __shared__ float hs[64][121];
  const int tid = threadIdx.x;
  for (int i = tid; i < 7680; i += 256) hs[i / 120][i % 120] = h1[i];
  __syncthreads();
  const int m = tid & 63;
  const int j = blockIdx.x * 4 + __builtin_amdgcn_readfirstlane(tid >> 6);
  const float* wj = W + j * 120;
  float a = bias[j];
  for (int k = 0; k < 120; ++k) a = fmaf(hs[m][k], wj[k], a);
  h2[m * 84 + j] = fmaxf(a, 0.0f);
}

// ---------------- Kernel 6: fc3 + quantum kernel head + sigmoid ------------
__global__ void final_kernel(
    const float* __restrict__ h2, const float* __restrict__ w3,
    const float* __restrict__ b3, const float* __restrict__ proto,
    const float* __restrict__ khw, const float* __restrict__ khb,
    float* __restrict__ out) {
  const int m = threadIdx.x;  // 64 lanes
  const float* h = h2 + m * 84;
  float z = b3[0];
  for (int k = 0; k < 84; ++k) z = fmaf(h[k], w3[k], z);
  float logit = khb[0];
#pragma unroll
  for (int p = 0; p < 10; ++p) {
    const float c = cosf((z - proto[p]) * 0.5f);
    const float c2 = c * c;
    logit = fmaf(c2 * c2, khw[p], logit);
  }
  const float pr = 1.0f / (1.0f + expf(-logit));
  out[m * 2 + 0] = pr;
  out[m * 2 + 1] = 1.0f - pr;
}

// ---------------------------------------------------------------------------
extern "C" void kernel_launch(void* const* d_in, const int* in_sizes, int n_in,
                              void* d_out, int out_size, void* d_ws, size_t ws_size,
                              hipStream_t stream) {
  const float* x    = (const float*)d_in[0];
  const float* w1   = (const float*)d_in[1];
  const float* b1   = (const float*)d_in[2];
  const float* w2   = (const float*)d_in[3];
  const float* b2   = (const float*)d_in[4];
  const float* fw1  = (const float*)d_in[5];
  const float* fb1  = (const float*)d_in[6];
  const float* fw2  = (const float*)d_in[7];
  const float* fb2  = (const float*)d_in[8];
  const float* fw3  = (const float*)d_in[9];
  const float* fb3  = (const float*)d_in[10];
  const float* prot = (const float*)d_in[11];
  const float* khw  = (const float*)d_in[12];
  const float* khb  = (const float*)d_in[13];
  float* out = (float*)d_out;

  float* ws = (float*)d_ws;
  // pool1 (dead after conv2) is aliased by fc1 partials (written after).
  float* pool1 = ws;                           // 64*123*123*6 = 5,809,536 f
  float* part  = ws;                           // 582*7680     = 4,469,760 f (alias)
  float* A     = ws + 5809536;                 // 64*55872     = 3,575,808 f
  float* h1    = A + 3575808;                  // 7680 f
  float* h2    = h1 + 7680;                    // 5376 f

  conv1_pool <<<dim3(8, 64), 256, 0, stream>>>(x, w1, b1, pool1);
  conv2_pool <<<dim3(25, 64), 256, 0, stream>>>(pool1, w2, b2, A);
  fc1_partial<<<dim3(NCHUNK), 256, 0, stream>>>(A, fw1, part);
  fc1_reduce <<<dim3(240), 256, 0, stream>>>(part, fb1, h1);
  fc2_kernel <<<dim3(21), 256, 0, stream>>>(h1, fw2, fb2, h2);
  final_kernel<<<dim3(1), 64, 0, stream>>>(h2, fw3, fb3, prot, khw, khb, out);
}